// Round 1
// baseline (275.850 us; speedup 1.0000x reference)
//
#include <hip/hip_runtime.h>

// QuantDenseModelLarge: x[131072,256] -> (QuantLinear 4b + BN scale/bias + QuantReLU 8b) x3 -> Linear -> out[131072,12]
//
// Strategy (round 0 baseline):
//  - Kernel 1: fake-quantize all four weight tensors on device (per-tensor symmetric,
//    round-half-even like jnp.round), store TRANSPOSED (k-major) in d_ws so the main
//    kernel reads weights as contiguous wave-uniform scalar loads (s_load_dwordx16).
//  - Kernel 2: fully fused MLP, one row per thread, 256 rows per block.
//    x staged via LDS in 32-col chunks for coalescing; all activations register-resident;
//    layers 2/3/out fully unrolled (static register indexing only).

namespace {
constexpr int B_   = 131072;
constexpr int IN_  = 256;
constexpr int H_   = 58;
constexpr int C_   = 12;

// ws layout (floats), all transposed k-major: WT[k*odim + o]
constexpr int W1T_OFF = 0;                      // [256][58]
constexpr int W2T_OFF = W1T_OFF + H_ * IN_;     // [58][58]
constexpr int W3T_OFF = W2T_OFF + H_ * H_;      // [58][58]
constexpr int WOT_OFF = W3T_OFF + H_ * H_;      // [58][12]
}

__global__ void quantize_weights_kernel(
    const float* __restrict__ W1, const float* __restrict__ W2,
    const float* __restrict__ W3, const float* __restrict__ Wo,
    float* __restrict__ ws)
{
  __shared__ float red[256];
  const float* W; float* outT; int odim, idim;
  switch (blockIdx.x) {
    case 0:  W = W1; outT = ws + W1T_OFF; odim = H_; idim = IN_; break;
    case 1:  W = W2; outT = ws + W2T_OFF; odim = H_; idim = H_;  break;
    case 2:  W = W3; outT = ws + W3T_OFF; odim = H_; idim = H_;  break;
    default: W = Wo; outT = ws + WOT_OFF; odim = C_; idim = H_;  break;
  }
  const int n = odim * idim;
  const int t = threadIdx.x;

  float m = 0.f;
  for (int i = t; i < n; i += 256) m = fmaxf(m, fabsf(W[i]));
  red[t] = m;
  __syncthreads();
  for (int s = 128; s > 0; s >>= 1) {
    if (t < s) red[t] = fmaxf(red[t], red[t + s]);
    __syncthreads();
  }
  const float scale = red[0] / 7.0f;  // qmax = 2^(4-1)-1 = 7, per-tensor symmetric

  for (int i = t; i < n; i += 256) {
    const int o = i / idim;
    const int k = i - o * idim;
    float q = rintf(W[i] / scale);            // round-half-even == jnp.round
    q = fminf(fmaxf(q, -7.f), 7.f);
    outT[k * odim + o] = q * scale;
  }
}

__global__ __launch_bounds__(256, 2) void fused_mlp_kernel(
    const float* __restrict__ x,
    const float* __restrict__ ws,
    const float* __restrict__ g1, const float* __restrict__ b1, const float* __restrict__ s1p,
    const float* __restrict__ g2, const float* __restrict__ b2, const float* __restrict__ s2p,
    const float* __restrict__ g3, const float* __restrict__ b3, const float* __restrict__ s3p,
    const float* __restrict__ bo,
    float* __restrict__ out)
{
  // 36 = 32 cols + 4 pad: keeps rows 16B-aligned for float4 LDS ops and
  // spreads b128 accesses across bank groups (stride 36 mod 32 = 4).
  __shared__ float xs[256][36];

  const int t = threadIdx.x;
  const size_t rowbase = (size_t)blockIdx.x * 256;

  const float* __restrict__ W1T = ws + W1T_OFF;
  const float* __restrict__ W2T = ws + W2T_OFF;
  const float* __restrict__ W3T = ws + W3T_OFF;
  const float* __restrict__ WoT = ws + WOT_OFF;

  float acc[H_];
#pragma unroll
  for (int h = 0; h < H_; ++h) acc[h] = 0.f;

  const float* xblk = x + rowbase * IN_;

  // ---- Layer 1: [256 rows] x [256 -> 58], x staged through LDS in 32-col chunks ----
  for (int kc = 0; kc < IN_; kc += 32) {
    // cooperative coalesced load: 256 rows x 32 cols = 2048 float4
#pragma unroll
    for (int i = 0; i < 8; ++i) {
      const int F = t + (i << 8);
      const int r = F >> 3;          // row within tile
      const int j = F & 7;           // float4 index within 32-col chunk
      float4 v = *(const float4*)(xblk + (size_t)r * IN_ + kc + (j << 2));
      *(float4*)&xs[r][j << 2] = v;
    }
    __syncthreads();

#pragma unroll
    for (int j = 0; j < 8; ++j) {
      float4 xv = *(const float4*)&xs[t][j << 2];
#pragma unroll
      for (int c = 0; c < 4; ++c) {
        const float xc = (c == 0) ? xv.x : (c == 1) ? xv.y : (c == 2) ? xv.z : xv.w;
        const float* __restrict__ wrow = W1T + (kc + (j << 2) + c) * H_;  // contiguous, wave-uniform
#pragma unroll
        for (int h = 0; h < H_; ++h) acc[h] = fmaf(xc, wrow[h], acc[h]);
      }
    }
    __syncthreads();  // xs reads done before next chunk overwrites
  }

  // ---- BN + QuantReLU 1 ----
  const float s1 = s1p[0];
  float h1[H_];
#pragma unroll
  for (int h = 0; h < H_; ++h) {
    const float y = fmaf(acc[h], g1[h], b1[h]);
    const float q = fminf(rintf(fmaxf(y, 0.f) / s1), 255.f);
    h1[h] = q * s1;
  }

  // ---- Layer 2 (58x58, fully unrolled, register-resident) ----
  float y2[H_];
#pragma unroll
  for (int h = 0; h < H_; ++h) y2[h] = 0.f;
#pragma unroll
  for (int k = 0; k < H_; ++k) {
    const float a = h1[k];
    const float* __restrict__ wrow = W2T + k * H_;
#pragma unroll
    for (int h = 0; h < H_; ++h) y2[h] = fmaf(a, wrow[h], y2[h]);
  }
  const float s2 = s2p[0];
#pragma unroll
  for (int h = 0; h < H_; ++h) {
    const float y = fmaf(y2[h], g2[h], b2[h]);
    const float q = fminf(rintf(fmaxf(y, 0.f) / s2), 255.f);
    y2[h] = q * s2;
  }

  // ---- Layer 3 (reuse h1 registers as accumulator) ----
#pragma unroll
  for (int h = 0; h < H_; ++h) h1[h] = 0.f;
#pragma unroll
  for (int k = 0; k < H_; ++k) {
    const float a = y2[k];
    const float* __restrict__ wrow = W3T + k * H_;
#pragma unroll
    for (int h = 0; h < H_; ++h) h1[h] = fmaf(a, wrow[h], h1[h]);
  }
  const float s3 = s3p[0];
#pragma unroll
  for (int h = 0; h < H_; ++h) {
    const float y = fmaf(h1[h], g3[h], b3[h]);
    const float q = fminf(rintf(fmaxf(y, 0.f) / s3), 255.f);
    h1[h] = q * s3;
  }

  // ---- Output layer: 58 -> 12 + bias ----
  float o[C_];
#pragma unroll
  for (int c = 0; c < C_; ++c) o[c] = bo[c];
#pragma unroll
  for (int k = 0; k < H_; ++k) {
    const float a = h1[k];
    const float* __restrict__ wrow = WoT + k * C_;
#pragma unroll
    for (int c = 0; c < C_; ++c) o[c] = fmaf(a, wrow[c], o[c]);
  }

  // out row = 12 floats = 48B, every row 16B-aligned; lanes write consecutive rows
  float* orow = out + (rowbase + t) * C_;
  *(float4*)(orow + 0) = make_float4(o[0], o[1], o[2],  o[3]);
  *(float4*)(orow + 4) = make_float4(o[4], o[5], o[6],  o[7]);
  *(float4*)(orow + 8) = make_float4(o[8], o[9], o[10], o[11]);
}

extern "C" void kernel_launch(void* const* d_in, const int* in_sizes, int n_in,
                              void* d_out, int out_size, void* d_ws, size_t ws_size,
                              hipStream_t stream) {
  // setup_inputs order:
  // 0:x 1:W1 2:g1 3:b1 4:s1 5:W2 6:g2 7:b2 8:s2 9:W3 10:g3 11:b3 12:s3 13:Wo 14:bo
  const float* x  = (const float*)d_in[0];
  const float* W1 = (const float*)d_in[1];
  const float* g1 = (const float*)d_in[2];
  const float* b1 = (const float*)d_in[3];
  const float* s1 = (const float*)d_in[4];
  const float* W2 = (const float*)d_in[5];
  const float* g2 = (const float*)d_in[6];
  const float* b2 = (const float*)d_in[7];
  const float* s2 = (const float*)d_in[8];
  const float* W3 = (const float*)d_in[9];
  const float* g3 = (const float*)d_in[10];
  const float* b3 = (const float*)d_in[11];
  const float* s3 = (const float*)d_in[12];
  const float* Wo = (const float*)d_in[13];
  const float* bo = (const float*)d_in[14];

  float* ws  = (float*)d_ws;
  float* out = (float*)d_out;

  quantize_weights_kernel<<<4, 256, 0, stream>>>(W1, W2, W3, Wo, ws);

  fused_mlp_kernel<<<B_ / 256, 256, 0, stream>>>(
      x, ws, g1, b1, s1, g2, b2, s2, g3, b3, s3, bo, out);
}

// Round 6
// 62.014 us; speedup vs baseline: 4.4482x; 4.4482x over previous
//
#include <hip/hip_runtime.h>
#include <stdint.h>

// QuantDenseModelLarge on gfx950 — MFMA formulation (round 4 = round 3 + param-load fix).
// Round-3 failure root cause: `if (t < PAR_FLOATS) pars[t] = ...` with 256 threads
// loaded only pars[0..255]; pars[256..403] (layer-3 params, bo, inv1/inv2/inv3/So)
// were uninitialized LDS -> garbage quantization scales. Fixed with a strided loop.
//
// Exact identities:
//   quant weights = qw * sw, qw int in [-7,7]  -> exact in bf16
//   QuantReLU out = qa * s,  qa int in [0,255] -> exact in bf16
//   layers 2/3/out: D = sum(qa*qw) exact in f32; y = D*(s*sw)
//   layer 1: x == hi + lo1 + lo2 EXACTLY (3 bf16 truncation limbs cover 24 bits)
//
// MFMA layout (hardware-verified via learn_hip m89/m92 ref-checked GEMMs):
//   A (16x32): lane l holds A[m = l&15][k = 8*(l>>4) + j], j=0..7
//   B (32x16): lane l holds B[k = 8*(l>>4) + j][n = l&15]
//   C/D      : lane l, reg r holds D[row = 4*(l>>4) + r][col = l&15]

typedef __attribute__((ext_vector_type(4))) float  f32x4;
typedef __attribute__((ext_vector_type(8))) short  bf16x8;
typedef __attribute__((ext_vector_type(4))) unsigned int u32x4;

namespace {
constexpr int B_  = 131072;
constexpr int IN_ = 256;
constexpr int H_  = 58;
constexpr int C_  = 12;

// ws byte offsets
constexpr int W1F = 0;        // [ht4][kt8][lane64][j8] bf16 = 32768 B
constexpr int W2F = 32768;    // [ht4][kt2][lane64][j8] bf16 =  8192 B
constexpr int W3F = 40960;    //                                8192 B
constexpr int WOF = 49152;    // [kt2][lane64][j8]      bf16 =  2048 B
constexpr int PAR = 51200;    // 3*64 {A,b} f32 | bo[16] | {inv1,inv2,inv3,So}
constexpr int PAR_FLOATS = 404;
constexpr int PITCH = 144;    // bounce-tile row pitch (bytes): 128 data + 16 pad
}

__device__ __forceinline__ uint32_t fu(float f) { return __float_as_uint(f); }
__device__ __forceinline__ float    uf(uint32_t u) { return __uint_as_float(u); }
__device__ __forceinline__ float    truncbf(float v) { return uf(fu(v) & 0xffff0000u); }
// pack bf16(a) into low16, bf16(b) into high16 (truncation; exact for ints/limbs)
__device__ __forceinline__ uint32_t packbf(float a, float b) {
  return (fu(a) >> 16) | (fu(b) & 0xffff0000u);
}

__device__ __forceinline__ f32x4 MFMA(u32x4 a, bf16x8 b, f32x4 c) {
  union { u32x4 u; bf16x8 s; } ua; ua.u = a;
  return __builtin_amdgcn_mfma_f32_16x16x32_bf16(ua.s, b, c, 0, 0, 0);
}

// ---------------- prep: quantize + fragment-major arrange + param tables ----------------
__global__ void prep_kernel(
    const float* __restrict__ W1, const float* __restrict__ W2,
    const float* __restrict__ W3, const float* __restrict__ Wo,
    const float* __restrict__ g1, const float* __restrict__ b1, const float* __restrict__ s1,
    const float* __restrict__ g2, const float* __restrict__ b2, const float* __restrict__ s2,
    const float* __restrict__ g3, const float* __restrict__ b3, const float* __restrict__ s3,
    const float* __restrict__ bo,
    uint8_t* __restrict__ wsb)
{
  __shared__ float red[256];
  const int t = threadIdx.x;
  const int blk = blockIdx.x;
  const float* W; int n;
  switch (blk) {
    case 0: W = W1; n = H_ * IN_; break;
    case 1: W = W2; n = H_ * H_;  break;
    case 2: W = W3; n = H_ * H_;  break;
    default: W = Wo; n = C_ * H_; break;
  }
  float m = 0.f;
  for (int i = t; i < n; i += 256) m = fmaxf(m, fabsf(W[i]));
  red[t] = m;
  __syncthreads();
  for (int s = 128; s > 0; s >>= 1) { if (t < s) red[t] = fmaxf(red[t], red[t + s]); __syncthreads(); }
  const float sw = red[0] / 7.0f;   // per-tensor symmetric, qmax = 7

  float* pp = (float*)(wsb + PAR);

  if (blk == 0) {
    unsigned short* fr = (unsigned short*)(wsb + W1F);
    for (int i = t; i < 16384; i += 256) {
      const int j = i & 7, ln = (i >> 3) & 63, kt = (i >> 9) & 7, ht = (i >> 12) & 3;
      const int h = (ht << 4) | (ln & 15);
      const int k = (kt << 5) | (((ln >> 4) & 3) << 3) | j;
      float q = 0.f;
      if (h < H_) q = fminf(fmaxf(rintf(W1[h * IN_ + k] / sw), -7.f), 7.f);
      fr[i] = (unsigned short)(fu(q) >> 16);   // small ints exact in bf16
    }
    if (t < 64) {
      pp[2 * t]     = (t < H_) ? sw * g1[t] : 0.f;
      pp[2 * t + 1] = (t < H_) ? b1[t] : 0.f;
    }
    if (t == 0) pp[400] = 1.0f / s1[0];
  } else if (blk == 1) {
    unsigned short* fr = (unsigned short*)(wsb + W2F);
    for (int i = t; i < 4096; i += 256) {
      const int j = i & 7, ln = (i >> 3) & 63, kt = (i >> 9) & 1, ht = (i >> 10) & 3;
      const int h = (ht << 4) | (ln & 15);
      const int k = (kt << 5) | (((ln >> 4) & 3) << 3) | j;
      float q = 0.f;
      if (h < H_ && k < H_) q = fminf(fmaxf(rintf(W2[h * H_ + k] / sw), -7.f), 7.f);
      fr[i] = (unsigned short)(fu(q) >> 16);
    }
    if (t < 64) {
      pp[128 + 2 * t]     = (t < H_) ? s1[0] * sw * g2[t] : 0.f;
      pp[128 + 2 * t + 1] = (t < H_) ? b2[t] : 0.f;
    }
    if (t == 0) pp[401] = 1.0f / s2[0];
  } else if (blk == 2) {
    unsigned short* fr = (unsigned short*)(wsb + W3F);
    for (int i = t; i < 4096; i += 256) {
      const int j = i & 7, ln = (i >> 3) & 63, kt = (i >> 9) & 1, ht = (i >> 10) & 3;
      const int h = (ht << 4) | (ln & 15);
      const int k = (kt << 5) | (((ln >> 4) & 3) << 3) | j;
      float q = 0.f;
      if (h < H_ && k < H_) q = fminf(fmaxf(rintf(W3[h * H_ + k] / sw), -7.f), 7.f);
      fr[i] = (unsigned short)(fu(q) >> 16);
    }
    if (t < 64) {
      pp[256 + 2 * t]     = (t < H_) ? s2[0] * sw * g3[t] : 0.f;
      pp[256 + 2 * t + 1] = (t < H_) ? b3[t] : 0.f;
    }
    if (t == 0) pp[402] = 1.0f / s3[0];
  } else {
    unsigned short* fr = (unsigned short*)(wsb + WOF);
    for (int i = t; i < 1024; i += 256) {
      const int j = i & 7, ln = (i >> 3) & 63, kt = (i >> 9) & 1;
      const int h = ln & 15;
      const int k = (kt << 5) | (((ln >> 4) & 3) << 3) | j;
      float q = 0.f;
      if (h < C_ && k < H_) q = fminf(fmaxf(rintf(Wo[h * H_ + k] / sw), -7.f), 7.f);
      fr[i] = (unsigned short)(fu(q) >> 16);
    }
    if (t < 16) pp[384 + t] = (t < C_) ? bo[t] : 0.f;
    if (t == 0) pp[403] = s3[0] * sw;
  }
}

// ---------------- epilogue: BN + QuantReLU -> bf16 ints -> per-wave LDS bounce -> B-frags ----------------
__device__ __forceinline__ void epilog(
    const f32x4 (&acc)[4], const float* __restrict__ pars, int L, float inv,
    uint8_t* bw, int g, int c, bf16x8 (&bfr)[2])
{
  const float* pb = pars + L * 128 + 8 * g;   // {A(h),b(h)} pairs, h = 16ht+4g+r
#pragma unroll
  for (int ht = 0; ht < 4; ++ht) {
    float q[4];
#pragma unroll
    for (int r = 0; r < 4; ++r) {
      const float y = fmaf(acc[ht][r], pb[32 * ht + 2 * r], pb[32 * ht + 2 * r + 1]);
      q[r] = fminf(rintf(fmaxf(y, 0.f) * inv), 255.f);
    }
    uint8_t* bp = bw + c * PITCH + 32 * ht + 8 * g;   // row c, bytes 2h..2h+7
    *(uint32_t*)(bp)     = packbf(q[0], q[1]);
    *(uint32_t*)(bp + 4) = packbf(q[2], q[3]);
  }
  // same-wave cross-lane exchange: DS ops from one wave are processed in order
#pragma unroll
  for (int kt = 0; kt < 2; ++kt) {
    const uint8_t* rp = bw + c * PITCH + 64 * kt + 16 * g;  // k = 32kt+8g+j
    union { u32x4 u; bf16x8 s; } uv;
    uv.u = *(const u32x4*)rp;
    bfr[kt] = uv.s;
  }
}

__global__ __launch_bounds__(256, 2) void fused_mfma_kernel(
    const float* __restrict__ x, const uint8_t* __restrict__ wsb,
    float* __restrict__ out)
{
  __shared__ __align__(16) uint8_t bnc[4][16 * PITCH];  // per-wave bounce tiles
  __shared__ __align__(16) float pars[PAR_FLOATS];

  const int t = threadIdx.x;
  const int w = t >> 6, l = t & 63, g = (l >> 4) & 3, c = l & 15;
  const size_t rowbase = (size_t)blockIdx.x * 64;

  // FIX (round 3 bug): strided load — 404 floats, 256 threads.
  for (int i = t; i < PAR_FLOATS; i += 256) pars[i] = ((const float*)(wsb + PAR))[i];
  __syncthreads();   // only block-wide barrier

  const float inv1 = pars[400], inv2 = pars[401], inv3 = pars[402], So = pars[403];

  // this lane's batch row (B-fragment n = l&15); k-slice owned: 8g..8g+7 (+32s)
  const float* __restrict__ xrow = x + (rowbase + 16 * w + c) * IN_;

  f32x4 acc[4];
#pragma unroll
  for (int ht = 0; ht < 4; ++ht) acc[ht] = f32x4{0.f, 0.f, 0.f, 0.f};

  // ---- Layer 1: 8 k-tiles of 32, 3 exact bf16 limbs ----
#pragma unroll
  for (int s = 0; s < 8; ++s) {
    u32x4 wf[4];
#pragma unroll
    for (int ht = 0; ht < 4; ++ht)
      wf[ht] = *(const u32x4*)(wsb + W1F + (size_t)(((ht * 8 + s) * 64) + l) * 16);

    const f32x4 e0 = *(const f32x4*)(xrow + 32 * s + 8 * g);
    const f32x4 e1 = *(const f32x4*)(xrow + 32 * s + 8 * g + 4);
    const float el[8] = {e0.x, e0.y, e0.z, e0.w, e1.x, e1.y, e1.z, e1.w};

    float d[8], e2[8];
#pragma unroll
    for (int q = 0; q < 8; ++q) d[q] = el[q] - truncbf(el[q]);   // exact
#pragma unroll
    for (int q = 0; q < 8; ++q) e2[q] = d[q] - truncbf(d[q]);    // exact

    union { uint32_t u[4]; bf16x8 v; } bh, bl1, bl2;
#pragma unroll
    for (int q = 0; q < 4; ++q) {
      bh.u[q]  = packbf(el[2 * q], el[2 * q + 1]);
      bl1.u[q] = packbf(d[2 * q],  d[2 * q + 1]);
      bl2.u[q] = packbf(e2[2 * q], e2[2 * q + 1]);
    }
#pragma unroll
    for (int ht = 0; ht < 4; ++ht) acc[ht] = MFMA(wf[ht], bh.v,  acc[ht]);
#pragma unroll
    for (int ht = 0; ht < 4; ++ht) acc[ht] = MFMA(wf[ht], bl1.v, acc[ht]);
#pragma unroll
    for (int ht = 0; ht < 4; ++ht) acc[ht] = MFMA(wf[ht], bl2.v, acc[ht]);
  }

  uint8_t* bw = &bnc[w][0];
  bf16x8 bfr[2];

  // ---- Layer 2 ----
  epilog(acc, pars, 0, inv1, bw, g, c, bfr);
  f32x4 a2[4];
#pragma unroll
  for (int ht = 0; ht < 4; ++ht) a2[ht] = f32x4{0.f, 0.f, 0.f, 0.f};
#pragma unroll
  for (int kt = 0; kt < 2; ++kt) {
#pragma unroll
    for (int ht = 0; ht < 4; ++ht) {
      const u32x4 wf = *(const u32x4*)(wsb + W2F + (size_t)(((ht * 2 + kt) * 64) + l) * 16);
      a2[ht] = MFMA(wf, bfr[kt], a2[ht]);
    }
  }

  // ---- Layer 3 ----
  epilog(a2, pars, 1, inv2, bw, g, c, bfr);
  f32x4 a3[4];
#pragma unroll
  for (int ht = 0; ht < 4; ++ht) a3[ht] = f32x4{0.f, 0.f, 0.f, 0.f};
#pragma unroll
  for (int kt = 0; kt < 2; ++kt) {
#pragma unroll
    for (int ht = 0; ht < 4; ++ht) {
      const u32x4 wf = *(const u32x4*)(wsb + W3F + (size_t)(((ht * 2 + kt) * 64) + l) * 16);
      a3[ht] = MFMA(wf, bfr[kt], a3[ht]);
    }
  }

  // ---- Output layer ----
  epilog(a3, pars, 2, inv3, bw, g, c, bfr);
  f32x4 ao = f32x4{0.f, 0.f, 0.f, 0.f};
#pragma unroll
  for (int kt = 0; kt < 2; ++kt) {
    const u32x4 wf = *(const u32x4*)(wsb + WOF + (size_t)((kt * 64) + l) * 16);
    ao = MFMA(wf, bfr[kt], ao);
  }

  const float bo0 = pars[384 + 4 * g + 0];
  const float bo1 = pars[384 + 4 * g + 1];
  const float bo2 = pars[384 + 4 * g + 2];
  const float bo3 = pars[384 + 4 * g + 3];
  f32x4 o;
  o.x = fmaf(ao.x, So, bo0);
  o.y = fmaf(ao.y, So, bo1);
  o.z = fmaf(ao.z, So, bo2);
  o.w = fmaf(ao.w, So, bo3);
  if (g < 3)  // out channels 4g..4g+3; only 0..11 exist
    *(f32x4*)(out + (rowbase + 16 * w + c) * C_ + 4 * g) = o;
}

extern "C" void kernel_launch(void* const* d_in, const int* in_sizes, int n_in,
                              void* d_out, int out_size, void* d_ws, size_t ws_size,
                              hipStream_t stream) {
  // 0:x 1:W1 2:g1 3:b1 4:s1 5:W2 6:g2 7:b2 8:s2 9:W3 10:g3 11:b3 12:s3 13:Wo 14:bo
  const float* x  = (const float*)d_in[0];
  const float* W1 = (const float*)d_in[1];
  const float* g1 = (const float*)d_in[2];
  const float* b1 = (const float*)d_in[3];
  const float* s1 = (const float*)d_in[4];
  const float* W2 = (const float*)d_in[5];
  const float* g2 = (const float*)d_in[6];
  const float* b2 = (const float*)d_in[7];
  const float* s2 = (const float*)d_in[8];
  const float* W3 = (const float*)d_in[9];
  const float* g3 = (const float*)d_in[10];
  const float* b3 = (const float*)d_in[11];
  const float* s3 = (const float*)d_in[12];
  const float* Wo = (const float*)d_in[13];
  const float* bo = (const float*)d_in[14];

  uint8_t* ws = (uint8_t*)d_ws;
  float* out = (float*)d_out;

  prep_kernel<<<4, 256, 0, stream>>>(W1, W2, W3, Wo, g1, b1, s1, g2, b2, s2,
                                     g3, b3, s3, bo, ws);
  fused_mfma_kernel<<<B_ / 64, 256, 0, stream>>>(x, ws, out);
}

// Round 7
// 61.920 us; speedup vs baseline: 4.4550x; 1.0015x over previous
//
#include <hip/hip_runtime.h>
#include <stdint.h>

// QuantDenseModelLarge on gfx950 — MFMA formulation.
// Round 7 = round 6 (passed, 62.0 µs) + occupancy bump: __launch_bounds__(256,2) -> (256,4).
// Theory: 2 waves/EU can't hide ~900cy HBM latency against ~160cy/k-tile compute;
// 4 waves/EU doubles in-flight loads. Register demand ~100 VGPR fits the 128 cap.
//
// Exact identities:
//   quant weights = qw * sw, qw int in [-7,7]  -> exact in bf16
//   QuantReLU out = qa * s,  qa int in [0,255] -> exact in bf16
//   layers 2/3/out: D = sum(qa*qw) exact in f32; y = D*(s*sw)
//   layer 1: x == hi + lo1 + lo2 EXACTLY (3 bf16 truncation limbs cover 24 bits)
//
// MFMA layout (hardware-verified via learn_hip m89/m92 ref-checked GEMMs):
//   A (16x32): lane l holds A[m = l&15][k = 8*(l>>4) + j], j=0..7
//   B (32x16): lane l holds B[k = 8*(l>>4) + j][n = l&15]
//   C/D      : lane l, reg r holds D[row = 4*(l>>4) + r][col = l&15]

typedef __attribute__((ext_vector_type(4))) float  f32x4;
typedef __attribute__((ext_vector_type(8))) short  bf16x8;
typedef __attribute__((ext_vector_type(4))) unsigned int u32x4;

namespace {
constexpr int B_  = 131072;
constexpr int IN_ = 256;
constexpr int H_  = 58;
constexpr int C_  = 12;

// ws byte offsets
constexpr int W1F = 0;        // [ht4][kt8][lane64][j8] bf16 = 32768 B
constexpr int W2F = 32768;    // [ht4][kt2][lane64][j8] bf16 =  8192 B
constexpr int W3F = 40960;    //                                8192 B
constexpr int WOF = 49152;    // [kt2][lane64][j8]      bf16 =  2048 B
constexpr int PAR = 51200;    // 3*64 {A,b} f32 | bo[16] | {inv1,inv2,inv3,So}
constexpr int PAR_FLOATS = 404;
constexpr int PITCH = 144;    // bounce-tile row pitch (bytes): 128 data + 16 pad
}

__device__ __forceinline__ uint32_t fu(float f) { return __float_as_uint(f); }
__device__ __forceinline__ float    uf(uint32_t u) { return __uint_as_float(u); }
__device__ __forceinline__ float    truncbf(float v) { return uf(fu(v) & 0xffff0000u); }
// pack bf16(a) into low16, bf16(b) into high16 (truncation; exact for ints/limbs)
__device__ __forceinline__ uint32_t packbf(float a, float b) {
  return (fu(a) >> 16) | (fu(b) & 0xffff0000u);
}

__device__ __forceinline__ f32x4 MFMA(u32x4 a, bf16x8 b, f32x4 c) {
  union { u32x4 u; bf16x8 s; } ua; ua.u = a;
  return __builtin_amdgcn_mfma_f32_16x16x32_bf16(ua.s, b, c, 0, 0, 0);
}

// ---------------- prep: quantize + fragment-major arrange + param tables ----------------
__global__ void prep_kernel(
    const float* __restrict__ W1, const float* __restrict__ W2,
    const float* __restrict__ W3, const float* __restrict__ Wo,
    const float* __restrict__ g1, const float* __restrict__ b1, const float* __restrict__ s1,
    const float* __restrict__ g2, const float* __restrict__ b2, const float* __restrict__ s2,
    const float* __restrict__ g3, const float* __restrict__ b3, const float* __restrict__ s3,
    const float* __restrict__ bo,
    uint8_t* __restrict__ wsb)
{
  __shared__ float red[256];
  const int t = threadIdx.x;
  const int blk = blockIdx.x;
  const float* W; int n;
  switch (blk) {
    case 0: W = W1; n = H_ * IN_; break;
    case 1: W = W2; n = H_ * H_;  break;
    case 2: W = W3; n = H_ * H_;  break;
    default: W = Wo; n = C_ * H_; break;
  }
  float m = 0.f;
  for (int i = t; i < n; i += 256) m = fmaxf(m, fabsf(W[i]));
  red[t] = m;
  __syncthreads();
  for (int s = 128; s > 0; s >>= 1) { if (t < s) red[t] = fmaxf(red[t], red[t + s]); __syncthreads(); }
  const float sw = red[0] / 7.0f;   // per-tensor symmetric, qmax = 7

  float* pp = (float*)(wsb + PAR);

  if (blk == 0) {
    unsigned short* fr = (unsigned short*)(wsb + W1F);
    for (int i = t; i < 16384; i += 256) {
      const int j = i & 7, ln = (i >> 3) & 63, kt = (i >> 9) & 7, ht = (i >> 12) & 3;
      const int h = (ht << 4) | (ln & 15);
      const int k = (kt << 5) | (((ln >> 4) & 3) << 3) | j;
      float q = 0.f;
      if (h < H_) q = fminf(fmaxf(rintf(W1[h * IN_ + k] / sw), -7.f), 7.f);
      fr[i] = (unsigned short)(fu(q) >> 16);   // small ints exact in bf16
    }
    if (t < 64) {
      pp[2 * t]     = (t < H_) ? sw * g1[t] : 0.f;
      pp[2 * t + 1] = (t < H_) ? b1[t] : 0.f;
    }
    if (t == 0) pp[400] = 1.0f / s1[0];
  } else if (blk == 1) {
    unsigned short* fr = (unsigned short*)(wsb + W2F);
    for (int i = t; i < 4096; i += 256) {
      const int j = i & 7, ln = (i >> 3) & 63, kt = (i >> 9) & 1, ht = (i >> 10) & 3;
      const int h = (ht << 4) | (ln & 15);
      const int k = (kt << 5) | (((ln >> 4) & 3) << 3) | j;
      float q = 0.f;
      if (h < H_ && k < H_) q = fminf(fmaxf(rintf(W2[h * H_ + k] / sw), -7.f), 7.f);
      fr[i] = (unsigned short)(fu(q) >> 16);
    }
    if (t < 64) {
      pp[128 + 2 * t]     = (t < H_) ? s1[0] * sw * g2[t] : 0.f;
      pp[128 + 2 * t + 1] = (t < H_) ? b2[t] : 0.f;
    }
    if (t == 0) pp[401] = 1.0f / s2[0];
  } else if (blk == 2) {
    unsigned short* fr = (unsigned short*)(wsb + W3F);
    for (int i = t; i < 4096; i += 256) {
      const int j = i & 7, ln = (i >> 3) & 63, kt = (i >> 9) & 1, ht = (i >> 10) & 3;
      const int h = (ht << 4) | (ln & 15);
      const int k = (kt << 5) | (((ln >> 4) & 3) << 3) | j;
      float q = 0.f;
      if (h < H_ && k < H_) q = fminf(fmaxf(rintf(W3[h * H_ + k] / sw), -7.f), 7.f);
      fr[i] = (unsigned short)(fu(q) >> 16);
    }
    if (t < 64) {
      pp[256 + 2 * t]     = (t < H_) ? s2[0] * sw * g3[t] : 0.f;
      pp[256 + 2 * t + 1] = (t < H_) ? b3[t] : 0.f;
    }
    if (t == 0) pp[402] = 1.0f / s3[0];
  } else {
    unsigned short* fr = (unsigned short*)(wsb + WOF);
    for (int i = t; i < 1024; i += 256) {
      const int j = i & 7, ln = (i >> 3) & 63, kt = (i >> 9) & 1;
      const int h = ln & 15;
      const int k = (kt << 5) | (((ln >> 4) & 3) << 3) | j;
      float q = 0.f;
      if (h < C_ && k < H_) q = fminf(fmaxf(rintf(Wo[h * H_ + k] / sw), -7.f), 7.f);
      fr[i] = (unsigned short)(fu(q) >> 16);
    }
    if (t < 16) pp[384 + t] = (t < C_) ? bo[t] : 0.f;
    if (t == 0) pp[403] = s3[0] * sw;
  }
}

// ---------------- epilogue: BN + QuantReLU -> bf16 ints -> per-wave LDS bounce -> B-frags ----------------
__device__ __forceinline__ void epilog(
    const f32x4 (&acc)[4], const float* __restrict__ pars, int L, float inv,
    uint8_t* bw, int g, int c, bf16x8 (&bfr)[2])
{
  const float* pb = pars + L * 128 + 8 * g;   // {A(h),b(h)} pairs, h = 16ht+4g+r
#pragma unroll
  for (int ht = 0; ht < 4; ++ht) {
    float q[4];
#pragma unroll
    for (int r = 0; r < 4; ++r) {
      const float y = fmaf(acc[ht][r], pb[32 * ht + 2 * r], pb[32 * ht + 2 * r + 1]);
      q[r] = fminf(rintf(fmaxf(y, 0.f) * inv), 255.f);
    }
    uint8_t* bp = bw + c * PITCH + 32 * ht + 8 * g;   // row c, bytes 2h..2h+7
    *(uint32_t*)(bp)     = packbf(q[0], q[1]);
    *(uint32_t*)(bp + 4) = packbf(q[2], q[3]);
  }
  // same-wave cross-lane exchange: DS ops from one wave are processed in order
#pragma unroll
  for (int kt = 0; kt < 2; ++kt) {
    const uint8_t* rp = bw + c * PITCH + 64 * kt + 16 * g;  // k = 32kt+8g+j
    union { u32x4 u; bf16x8 s; } uv;
    uv.u = *(const u32x4*)rp;
    bfr[kt] = uv.s;
  }
}

__global__ __launch_bounds__(256, 4) void fused_mfma_kernel(
    const float* __restrict__ x, const uint8_t* __restrict__ wsb,
    float* __restrict__ out)
{
  __shared__ __align__(16) uint8_t bnc[4][16 * PITCH];  // per-wave bounce tiles
  __shared__ __align__(16) float pars[PAR_FLOATS];

  const int t = threadIdx.x;
  const int w = t >> 6, l = t & 63, g = (l >> 4) & 3, c = l & 15;
  const size_t rowbase = (size_t)blockIdx.x * 64;

  // strided load — 404 floats, 256 threads
  for (int i = t; i < PAR_FLOATS; i += 256) pars[i] = ((const float*)(wsb + PAR))[i];
  __syncthreads();   // only block-wide barrier

  const float inv1 = pars[400], inv2 = pars[401], inv3 = pars[402], So = pars[403];

  // this lane's batch row (B-fragment n = l&15); k-slice owned: 8g..8g+7 (+32s)
  const float* __restrict__ xrow = x + (rowbase + 16 * w + c) * IN_;

  f32x4 acc[4];
#pragma unroll
  for (int ht = 0; ht < 4; ++ht) acc[ht] = f32x4{0.f, 0.f, 0.f, 0.f};

  // ---- Layer 1: 8 k-tiles of 32, 3 exact bf16 limbs ----
#pragma unroll
  for (int s = 0; s < 8; ++s) {
    u32x4 wf[4];
#pragma unroll
    for (int ht = 0; ht < 4; ++ht)
      wf[ht] = *(const u32x4*)(wsb + W1F + (size_t)(((ht * 8 + s) * 64) + l) * 16);

    const f32x4 e0 = *(const f32x4*)(xrow + 32 * s + 8 * g);
    const f32x4 e1 = *(const f32x4*)(xrow + 32 * s + 8 * g + 4);
    const float el[8] = {e0.x, e0.y, e0.z, e0.w, e1.x, e1.y, e1.z, e1.w};

    float d[8], e2[8];
#pragma unroll
    for (int q = 0; q < 8; ++q) d[q] = el[q] - truncbf(el[q]);   // exact
#pragma unroll
    for (int q = 0; q < 8; ++q) e2[q] = d[q] - truncbf(d[q]);    // exact

    union { uint32_t u[4]; bf16x8 v; } bh, bl1, bl2;
#pragma unroll
    for (int q = 0; q < 4; ++q) {
      bh.u[q]  = packbf(el[2 * q], el[2 * q + 1]);
      bl1.u[q] = packbf(d[2 * q],  d[2 * q + 1]);
      bl2.u[q] = packbf(e2[2 * q], e2[2 * q + 1]);
    }
#pragma unroll
    for (int ht = 0; ht < 4; ++ht) acc[ht] = MFMA(wf[ht], bh.v,  acc[ht]);
#pragma unroll
    for (int ht = 0; ht < 4; ++ht) acc[ht] = MFMA(wf[ht], bl1.v, acc[ht]);
#pragma unroll
    for (int ht = 0; ht < 4; ++ht) acc[ht] = MFMA(wf[ht], bl2.v, acc[ht]);
  }

  uint8_t* bw = &bnc[w][0];
  bf16x8 bfr[2];

  // ---- Layer 2 ----
  epilog(acc, pars, 0, inv1, bw, g, c, bfr);
  f32x4 a2[4];
#pragma unroll
  for (int ht = 0; ht < 4; ++ht) a2[ht] = f32x4{0.f, 0.f, 0.f, 0.f};
#pragma unroll
  for (int kt = 0; kt < 2; ++kt) {
#pragma unroll
    for (int ht = 0; ht < 4; ++ht) {
      const u32x4 wf = *(const u32x4*)(wsb + W2F + (size_t)(((ht * 2 + kt) * 64) + l) * 16);
      a2[ht] = MFMA(wf, bfr[kt], a2[ht]);
    }
  }

  // ---- Layer 3 ----
  epilog(a2, pars, 1, inv2, bw, g, c, bfr);
  f32x4 a3[4];
#pragma unroll
  for (int ht = 0; ht < 4; ++ht) a3[ht] = f32x4{0.f, 0.f, 0.f, 0.f};
#pragma unroll
  for (int kt = 0; kt < 2; ++kt) {
#pragma unroll
    for (int ht = 0; ht < 4; ++ht) {
      const u32x4 wf = *(const u32x4*)(wsb + W3F + (size_t)(((ht * 2 + kt) * 64) + l) * 16);
      a3[ht] = MFMA(wf, bfr[kt], a3[ht]);
    }
  }

  // ---- Output layer ----
  epilog(a3, pars, 2, inv3, bw, g, c, bfr);
  f32x4 ao = f32x4{0.f, 0.f, 0.f, 0.f};
#pragma unroll
  for (int kt = 0; kt < 2; ++kt) {
    const u32x4 wf = *(const u32x4*)(wsb + WOF + (size_t)((kt * 64) + l) * 16);
    ao = MFMA(wf, bfr[kt], ao);
  }

  const float bo0 = pars[384 + 4 * g + 0];
  const float bo1 = pars[384 + 4 * g + 1];
  const float bo2 = pars[384 + 4 * g + 2];
  const float bo3 = pars[384 + 4 * g + 3];
  f32x4 o;
  o.x = fmaf(ao.x, So, bo0);
  o.y = fmaf(ao.y, So, bo1);
  o.z = fmaf(ao.z, So, bo2);
  o.w = fmaf(ao.w, So, bo3);
  if (g < 3)  // out channels 4g..4g+3; only 0..11 exist
    *(f32x4*)(out + (rowbase + 16 * w + c) * C_ + 4 * g) = o;
}

extern "C" void kernel_launch(void* const* d_in, const int* in_sizes, int n_in,
                              void* d_out, int out_size, void* d_ws, size_t ws_size,
                              hipStream_t stream) {
  // 0:x 1:W1 2:g1 3:b1 4:s1 5:W2 6:g2 7:b2 8:s2 9:W3 10:g3 11:b3 12:s3 13:Wo 14:bo
  const float* x  = (const float*)d_in[0];
  const float* W1 = (const float*)d_in[1];
  const float* g1 = (const float*)d_in[2];
  const float* b1 = (const float*)d_in[3];
  const float* s1 = (const float*)d_in[4];
  const float* W2 = (const float*)d_in[5];
  const float* g2 = (const float*)d_in[6];
  const float* b2 = (const float*)d_in[7];
  const float* s2 = (const float*)d_in[8];
  const float* W3 = (const float*)d_in[9];
  const float* g3 = (const float*)d_in[10];
  const float* b3 = (const float*)d_in[11];
  const float* s3 = (const float*)d_in[12];
  const float* Wo = (const float*)d_in[13];
  const float* bo = (const float*)d_in[14];

  uint8_t* ws = (uint8_t*)d_ws;
  float* out = (float*)d_out;

  prep_kernel<<<4, 256, 0, stream>>>(W1, W2, W3, Wo, g1, b1, s1, g2, b2, s2,
                                     g3, b3, s3, bo, ws);
  fused_mfma_kernel<<<B_ / 64, 256, 0, stream>>>(x, ws, out);
}